// Round 2
// baseline (1619.065 us; speedup 1.0000x reference)
//
#include <hip/hip_runtime.h>
#include <math.h>

#define T_STEPS 512
#define BATCH   512

__device__ __forceinline__ float sigmoidf_(float x) {
    return 1.0f / (1.0f + __expf(-x));        // x<<0 -> 1/inf = 0, safe
}
__device__ __forceinline__ float tanhf_(float x) {
    float ax = fabsf(x);
    float e  = __expf(-2.0f * ax);            // in (0,1], never overflows
    float t  = (1.0f - e) / (1.0f + e);
    return copysignf(t, x);
}

// ---------------------------------------------------------------------------
// Kernel 1: layer-1 LSTM, fully fused scan.
// Grid 256 blocks (1/CU), 2 batch rows per block, NT=448 (7 waves).
//   tid < 400 : gate threads, w_ih1 row (64) + w_hh1 row (100) in registers;
//               compute gates for BOTH batch rows each step.
//   tid < 200 : update threads (b=tid/100, u=tid%100), c in register.
//   tid < 128 : prefetch next step's x rows (issued phase A, written phase B).
// ---------------------------------------------------------------------------
__global__ __launch_bounds__(448, 1) void lstm1_kernel(
    const float* __restrict__ x,      // [T,B,64]
    const float* __restrict__ w_ih,   // [400,64]
    const float* __restrict__ w_hh,   // [400,100]
    const float* __restrict__ b_ih, const float* __restrict__ b_hh,
    float* __restrict__ h1out)        // [T,B,100]
{
    __shared__ __align__(16) float xs[2][2][64];   // [buf][batch][k]
    __shared__ __align__(16) float hs[2][104];     // [batch][unit], padded
    __shared__ __align__(16) float gs[2][400];     // [batch][gate row]

    const int tid = threadIdx.x;
    const int b0  = blockIdx.x * 2;

    float wih[64], whh[100], bias = 0.0f;
    if (tid < 400) {
        bias = b_ih[tid] + b_hh[tid];
        #pragma unroll
        for (int k = 0; k < 64; ++k)  wih[k] = w_ih[tid * 64 + k];
        #pragma unroll
        for (int k = 0; k < 100; ++k) whh[k] = w_hh[tid * 100 + k];
    }

    if (tid < 128) xs[0][tid >> 6][tid & 63] = x[(size_t)b0 * 64 + tid];
    if (tid < 200) hs[tid / 100][tid % 100] = 0.0f;
    const int ub = (tid < 200) ? tid / 100 : 0;
    const int uu = (tid < 200) ? tid % 100 : 0;
    float c = 0.0f;
    __syncthreads();

    for (int t = 0; t < T_STEPS; ++t) {
        const int cur = t & 1, nxt = cur ^ 1;
        // phase A: issue prefetch, compute gates
        float pre = 0.0f;
        if (tid < 128 && t + 1 < T_STEPS)
            pre = x[((size_t)(t + 1) * BATCH + b0) * 64 + tid];
        if (tid < 400) {
            float a00 = bias, a01 = 0.0f, a10 = bias, a11 = 0.0f;
            const float4* xa = (const float4*)xs[cur][0];
            const float4* xb = (const float4*)xs[cur][1];
            #pragma unroll
            for (int k = 0; k < 16; ++k) {
                float4 va = xa[k], vb = xb[k];
                a00 = fmaf(va.x, wih[4*k+0], a00); a10 = fmaf(vb.x, wih[4*k+0], a10);
                a01 = fmaf(va.y, wih[4*k+1], a01); a11 = fmaf(vb.y, wih[4*k+1], a11);
                a00 = fmaf(va.z, wih[4*k+2], a00); a10 = fmaf(vb.z, wih[4*k+2], a10);
                a01 = fmaf(va.w, wih[4*k+3], a01); a11 = fmaf(vb.w, wih[4*k+3], a11);
            }
            const float4* h0 = (const float4*)hs[0];
            const float4* h1 = (const float4*)hs[1];
            #pragma unroll
            for (int k = 0; k < 25; ++k) {
                float4 v0 = h0[k], v1 = h1[k];
                a00 = fmaf(v0.x, whh[4*k+0], a00); a10 = fmaf(v1.x, whh[4*k+0], a10);
                a01 = fmaf(v0.y, whh[4*k+1], a01); a11 = fmaf(v1.y, whh[4*k+1], a11);
                a00 = fmaf(v0.z, whh[4*k+2], a00); a10 = fmaf(v1.z, whh[4*k+2], a10);
                a01 = fmaf(v0.w, whh[4*k+3], a01); a11 = fmaf(v1.w, whh[4*k+3], a11);
            }
            gs[0][tid] = a00 + a01;
            gs[1][tid] = a10 + a11;
        }
        __syncthreads();
        // phase B: write prefetch, elementwise update
        if (tid < 128 && t + 1 < T_STEPS) xs[nxt][tid >> 6][tid & 63] = pre;
        if (tid < 200) {
            float gi = gs[ub][uu],       gf = gs[ub][100 + uu];
            float gg = gs[ub][200 + uu], go = gs[ub][300 + uu];
            c = sigmoidf_(gf) * c + sigmoidf_(gi) * tanhf_(gg);
            float h = sigmoidf_(go) * tanhf_(c);
            hs[ub][uu] = h;
            h1out[((size_t)t * BATCH + b0 + ub) * 100 + uu] = h;
        }
        __syncthreads();
    }
}

// ---------------------------------------------------------------------------
// Kernel 2: layers 2+3 + final linear, software-pipelined in one scan.
//   iteration it: L2 does step it, L3 does step it-1, linear does step it-2.
// NT=512 (8 waves), grid 256, 2 batch rows per block.
//   tid   0..199 : L2 gates (both batches; wa=w_ih2 row[100], wb=w_hh2 row[50])
//   tid   0..99  : L2 update (c2)
//   tid   0..199 : prefetch h1 rows for it+1
//   tid 256..455 : L3 gates (ONE batch each: bb=(tid-256)/100, u3=%100;
//                  wa[0..49]=w_ih3 row, wb[0..24]=w_hh3 row)
//   tid 256..305 : L3 update (c3)
//   tid 456..457 : final linear (wa[0..24]=w_lin)
// Weight arrays are manually unioned (wa/wb) so VGPR = 150+misc, not 275.
// ---------------------------------------------------------------------------
__global__ __launch_bounds__(512, 1) void lstm23_kernel(
    const float* __restrict__ h1g,    // [T,B,100]
    const float* __restrict__ w_ih2, const float* __restrict__ w_hh2,
    const float* __restrict__ b_ih2, const float* __restrict__ b_hh2,
    const float* __restrict__ w_ih3, const float* __restrict__ w_hh3,
    const float* __restrict__ b_ih3, const float* __restrict__ b_hh3,
    const float* __restrict__ w_lin, const float* __restrict__ b_lin,
    float* __restrict__ out)          // [T,B,1]
{
    __shared__ __align__(16) float xs2[2][2][112];  // [buf][batch][k<100]
    __shared__ __align__(16) float h2s[2][56];      // [batch][u<50]
    __shared__ __align__(16) float g2 [2][200];     // [batch][gate row]
    __shared__ __align__(16) float x3b[2][2][56];   // [slot][batch][u<50]
    __shared__ __align__(16) float h3s[2][28];      // [batch][u<25]
    __shared__ __align__(16) float g3 [2][100];     // [batch][gate row]
    __shared__ __align__(16) float h3o[2][2][28];   // [slot][batch][u<25]

    const int tid = threadIdx.x;
    const int b0  = blockIdx.x * 2;

    float wa[100], wb[50], bias = 0.0f;
    int bb = 0, u3 = 0;
    if (tid < 200) {                       // L2 gate weights
        bias = b_ih2[tid] + b_hh2[tid];
        #pragma unroll
        for (int k = 0; k < 100; ++k) wa[k] = w_ih2[tid * 100 + k];
        #pragma unroll
        for (int k = 0; k < 50; ++k)  wb[k] = w_hh2[tid * 50 + k];
    } else if (tid >= 256 && tid < 456) {  // L3 gate weights
        int q = tid - 256; bb = q / 100; u3 = q % 100;
        bias = b_ih3[u3] + b_hh3[u3];
        #pragma unroll
        for (int k = 0; k < 50; ++k) wa[k] = w_ih3[u3 * 50 + k];
        #pragma unroll
        for (int k = 0; k < 25; ++k) wb[k] = w_hh3[u3 * 25 + k];
    } else if (tid >= 456 && tid < 458) {  // linear weights
        bias = b_lin[0];
        #pragma unroll
        for (int k = 0; k < 25; ++k) wa[k] = w_lin[k];
    }

    const int b2  = (tid < 100) ? tid / 50 : 0;
    const int u2  = (tid < 100) ? tid % 50 : 0;
    const int q3  = (tid >= 256 && tid < 306) ? (tid - 256) : 0;
    const int b3  = q3 / 25, u3u = q3 % 25;
    float c2 = 0.0f, c3 = 0.0f;

    if (tid < 200) xs2[0][tid / 100][tid % 100] = h1g[(size_t)b0 * 100 + tid];
    if (tid < 100) h2s[tid / 50][tid % 50] = 0.0f;
    if (tid >= 100 && tid < 150) { int q = tid - 100; h3s[q / 25][q % 25] = 0.0f; }
    __syncthreads();

    for (int it = 0; it < T_STEPS + 2; ++it) {
        // ---------------- phase A ----------------
        float pre = 0.0f;
        if (tid < 200 && it + 1 < T_STEPS)
            pre = h1g[((size_t)(it + 1) * BATCH + b0) * 100 + tid];

        if (tid < 200 && it < T_STEPS) {           // L2 gates, step it
            const int cur = it & 1;
            float a00 = bias, a01 = 0.0f, a10 = bias, a11 = 0.0f;
            const float4* xa = (const float4*)xs2[cur][0];
            const float4* xb = (const float4*)xs2[cur][1];
            #pragma unroll
            for (int k = 0; k < 25; ++k) {
                float4 va = xa[k], vb = xb[k];
                a00 = fmaf(va.x, wa[4*k+0], a00); a10 = fmaf(vb.x, wa[4*k+0], a10);
                a01 = fmaf(va.y, wa[4*k+1], a01); a11 = fmaf(vb.y, wa[4*k+1], a11);
                a00 = fmaf(va.z, wa[4*k+2], a00); a10 = fmaf(vb.z, wa[4*k+2], a10);
                a01 = fmaf(va.w, wa[4*k+3], a01); a11 = fmaf(vb.w, wa[4*k+3], a11);
            }
            const float2* h20 = (const float2*)h2s[0];
            const float2* h21 = (const float2*)h2s[1];
            #pragma unroll
            for (int k = 0; k < 25; ++k) {
                float2 v0 = h20[k], v1 = h21[k];
                a00 = fmaf(v0.x, wb[2*k+0], a00); a10 = fmaf(v1.x, wb[2*k+0], a10);
                a01 = fmaf(v0.y, wb[2*k+1], a01); a11 = fmaf(v1.y, wb[2*k+1], a11);
            }
            g2[0][tid] = a00 + a01;
            g2[1][tid] = a10 + a11;
        }

        if (tid >= 256 && tid < 456 && it >= 1 && it <= T_STEPS) {  // L3 gates, step it-1
            const int s3 = it - 1;
            float a0 = bias, a1 = 0.0f;
            const float2* xv = (const float2*)x3b[s3 & 1][bb];
            #pragma unroll
            for (int k = 0; k < 25; ++k) {
                float2 v = xv[k];
                a0 = fmaf(v.x, wa[2*k+0], a0);
                a1 = fmaf(v.y, wa[2*k+1], a1);
            }
            #pragma unroll
            for (int k = 0; k < 25; ++k)
                a0 = fmaf(h3s[bb][k], wb[k], a0);
            g3[bb][u3] = a0 + a1;
        }

        if (tid >= 456 && tid < 458 && it >= 2) {  // linear, step it-2
            const int sl = it - 2;
            const int lb = tid - 456;
            float o = bias;
            #pragma unroll
            for (int k = 0; k < 25; ++k)
                o = fmaf(h3o[sl & 1][lb][k], wa[k], o);
            out[(size_t)sl * BATCH + b0 + lb] = o;
        }
        __syncthreads();

        // ---------------- phase B ----------------
        if (tid < 200 && it + 1 < T_STEPS)
            xs2[(it + 1) & 1][tid / 100][tid % 100] = pre;

        if (tid < 100 && it < T_STEPS) {           // L2 update
            float gi = g2[b2][u2],       gf = g2[b2][50 + u2];
            float gg = g2[b2][100 + u2], go = g2[b2][150 + u2];
            c2 = sigmoidf_(gf) * c2 + sigmoidf_(gi) * tanhf_(gg);
            float h = sigmoidf_(go) * tanhf_(c2);
            h2s[b2][u2] = h;
            x3b[it & 1][b2][u2] = h;
        }

        if (tid >= 256 && tid < 306 && it >= 1 && it <= T_STEPS) {  // L3 update
            const int s3 = it - 1;
            float gi = g3[b3][u3u],      gf = g3[b3][25 + u3u];
            float gg = g3[b3][50 + u3u], go = g3[b3][75 + u3u];
            c3 = sigmoidf_(gf) * c3 + sigmoidf_(gi) * tanhf_(gg);
            float h = sigmoidf_(go) * tanhf_(c3);
            h3s[b3][u3u] = h;
            h3o[s3 & 1][b3][u3u] = h;
        }
        __syncthreads();
    }
}

extern "C" void kernel_launch(void* const* d_in, const int* in_sizes, int n_in,
                              void* d_out, int out_size, void* d_ws, size_t ws_size,
                              hipStream_t stream)
{
    const float* x     = (const float*)d_in[0];
    const float* w_ih1 = (const float*)d_in[1];
    const float* w_hh1 = (const float*)d_in[2];
    const float* b_ih1 = (const float*)d_in[3];
    const float* b_hh1 = (const float*)d_in[4];
    const float* w_ih2 = (const float*)d_in[5];
    const float* w_hh2 = (const float*)d_in[6];
    const float* b_ih2 = (const float*)d_in[7];
    const float* b_hh2 = (const float*)d_in[8];
    const float* w_ih3 = (const float*)d_in[9];
    const float* w_hh3 = (const float*)d_in[10];
    const float* b_ih3 = (const float*)d_in[11];
    const float* b_hh3 = (const float*)d_in[12];
    const float* w_lin = (const float*)d_in[13];
    const float* b_lin = (const float*)d_in[14];
    float* out = (float*)d_out;

    const size_t h1_bytes = (size_t)T_STEPS * BATCH * 100 * sizeof(float); // 104.9 MB
    if (ws_size < h1_bytes) return;  // soft-fail: distinguishes ws-too-small from crash

    float* h1 = (float*)d_ws;

    lstm1_kernel<<<BATCH / 2, 448, 0, stream>>>(x, w_ih1, w_hh1, b_ih1, b_hh1, h1);
    lstm23_kernel<<<BATCH / 2, 512, 0, stream>>>(h1,
                                                 w_ih2, w_hh2, b_ih2, b_hh2,
                                                 w_ih3, w_hh3, b_ih3, b_hh3,
                                                 w_lin, b_lin, out);
}